// Round 1
// baseline (636.415 us; speedup 1.0000x reference)
//
#include <hip/hip_runtime.h>
#include <hip/hip_bf16.h>

// Problem dims (from reference): x[16384,4096] fp32, v[4096,256] fp32, out[16384,1] fp32
#define B_DIM 16384
#define N_DIM 4096
#define F_DIM 256

typedef short bf16x8 __attribute__((ext_vector_type(8)));
typedef float f32x4 __attribute__((ext_vector_type(4)));

static __device__ __forceinline__ short f2bf(float f) {
    __hip_bfloat16 h = __float2bfloat16(f);
    union { __hip_bfloat16 h; short s; } u;
    u.h = h;
    return u.s;
}

// Kernel A: v[4096][256] fp32 -> vT[256][4096] bf16 (for contiguous B-fragment
// reads) and w[n] = sum_f v[n][f]^2 (fp32).
// block = 256 threads, each block handles 16 rows of v.
__global__ __launch_bounds__(256) void prep_kernel(const float* __restrict__ v,
                                                   __hip_bfloat16* __restrict__ vT,
                                                   float* __restrict__ w) {
    const int t = threadIdx.x;          // = f index
    const int n0 = blockIdx.x * 16;
    const int lane = t & 63;
    const int wid = t >> 6;
    __shared__ float part[16][4];

    float vals[16];
#pragma unroll
    for (int r = 0; r < 16; ++r) {
        vals[r] = v[(size_t)(n0 + r) * F_DIM + t];   // coalesced along f
    }
#pragma unroll
    for (int r = 0; r < 16; ++r) {
        float s = vals[r] * vals[r];
#pragma unroll
        for (int m = 1; m < 64; m <<= 1) s += __shfl_xor(s, m);
        if (lane == 0) part[r][wid] = s;
    }
    __syncthreads();
    if (t < 16) w[n0 + t] = part[t][0] + part[t][1] + part[t][2] + part[t][3];

    // transposed bf16 write: vT[f=t][n0..n0+15], 32B contiguous per thread
    ushort ob[16];
#pragma unroll
    for (int r = 0; r < 16; ++r) ob[r] = (ushort)f2bf(vals[r]);
    uint4* dst = reinterpret_cast<uint4*>(
        reinterpret_cast<ushort*>(vT) + (size_t)t * N_DIM + n0);
    dst[0] = *reinterpret_cast<uint4*>(&ob[0]);
    dst[1] = *reinterpret_cast<uint4*>(&ob[8]);
}

// Kernel B: fused GEMM + square-sum + second-term dot.
// grid = 512 blocks (32 rows each), block = 512 threads = 8 waves.
// wave layout: waverow = wid>>2 (2 row groups of 16), wavecol = wid&3 (4 col
// groups of 64). mfma_f32_16x16x32_bf16 per 16x16 col-fragment (4 per wave).
// A fragment: lane l reads x[mbase + (l&15)][k0 + (l>>4)*8 .. +8] (fp32->bf16).
// B fragment: lane l reads vT[col][k0 + (l>>4)*8 .. +8] (16B contiguous).
__global__ __launch_bounds__(512) void fm_kernel(const float* __restrict__ x,
                                                 const __hip_bfloat16* __restrict__ vT,
                                                 const float* __restrict__ w,
                                                 float* __restrict__ out) {
    const int tid = threadIdx.x;
    const int lane = tid & 63;
    const int wid = tid >> 6;
    const int wavecol = wid & 3;      // 0..3 -> cols wavecol*64
    const int waverow = wid >> 2;     // 0..1 -> rows waverow*16
    const int l15 = lane & 15;
    const int koff = lane >> 4;       // 0..3

    const int mbase = blockIdx.x * 32 + waverow * 16;
    const float* xrow = x + (size_t)(mbase + l15) * N_DIM + koff * 8;
    const ushort* vbase = reinterpret_cast<const ushort*>(vT)
                        + (size_t)(wavecol * 64 + l15) * N_DIM + koff * 8;
    const float* wbase = w + koff * 8;

    f32x4 acc[4] = {};   // zero-init accumulators (16 fp32/lane)
    float s2 = 0.f;

#pragma unroll 2
    for (int k0 = 0; k0 < N_DIM; k0 += 32) {
        const float4 alo = *reinterpret_cast<const float4*>(xrow + k0);
        const float4 ahi = *reinterpret_cast<const float4*>(xrow + k0 + 4);

        bf16x8 a;
        a[0] = f2bf(alo.x); a[1] = f2bf(alo.y); a[2] = f2bf(alo.z); a[3] = f2bf(alo.w);
        a[4] = f2bf(ahi.x); a[5] = f2bf(ahi.y); a[6] = f2bf(ahi.z); a[7] = f2bf(ahi.w);

        if (wavecol == 0) {
            const float4 wlo = *reinterpret_cast<const float4*>(wbase + k0);
            const float4 whi = *reinterpret_cast<const float4*>(wbase + k0 + 4);
            s2 += alo.x * alo.x * wlo.x + alo.y * alo.y * wlo.y
                + alo.z * alo.z * wlo.z + alo.w * alo.w * wlo.w
                + ahi.x * ahi.x * whi.x + ahi.y * ahi.y * whi.y
                + ahi.z * ahi.z * whi.z + ahi.w * ahi.w * whi.w;
        }

#pragma unroll
        for (int cf = 0; cf < 4; ++cf) {
            bf16x8 b = *reinterpret_cast<const bf16x8*>(
                vbase + (size_t)cf * 16 * N_DIM + k0);
            acc[cf] = __builtin_amdgcn_mfma_f32_16x16x32_bf16(a, b, acc[cf], 0, 0, 0);
        }
    }

    // Epilogue: S1[row] = sum over all 256 cols of y^2.
    // C/D layout: col = lane&15 (within fragment), row = (lane>>4)*4 + reg.
    __shared__ float red[32][4];
    __shared__ float s2s[32];

#pragma unroll
    for (int j = 0; j < 4; ++j) {
        float s = 0.f;
#pragma unroll
        for (int cf = 0; cf < 4; ++cf) { const float y = acc[cf][j]; s += y * y; }
#pragma unroll
        for (int m = 1; m < 16; m <<= 1) s += __shfl_xor(s, m);  // sum 16 cols in group
        if (l15 == 0) red[waverow * 16 + koff * 4 + j][wavecol] = s;
    }

    if (wavecol == 0) {
        // s2 per lane is partial for row l15 over k-slice koff; sum over koff.
        s2 += __shfl_xor(s2, 16);
        s2 += __shfl_xor(s2, 32);
        if (lane < 16) s2s[waverow * 16 + lane] = s2;
    }
    __syncthreads();

    if (tid < 32) {
        const float s1 = red[tid][0] + red[tid][1] + red[tid][2] + red[tid][3];
        out[(size_t)blockIdx.x * 32 + tid] = 0.5f * (s1 - s2s[tid]);
    }
}

extern "C" void kernel_launch(void* const* d_in, const int* in_sizes, int n_in,
                              void* d_out, int out_size, void* d_ws, size_t ws_size,
                              hipStream_t stream) {
    const float* x = (const float*)d_in[0];
    const float* v = (const float*)d_in[1];
    float* out = (float*)d_out;

    // ws layout: [0, 2MB) vT bf16[256*4096]; then w fp32[4096]
    __hip_bfloat16* vT = (__hip_bfloat16*)d_ws;
    float* w = (float*)((char*)d_ws + (size_t)F_DIM * N_DIM * sizeof(__hip_bfloat16));

    prep_kernel<<<N_DIM / 16, 256, 0, stream>>>(v, vT, w);
    fm_kernel<<<B_DIM / 32, 512, 0, stream>>>(x, vT, w, out);
}

// Round 3
// 417.763 us; speedup vs baseline: 1.5234x; 1.5234x over previous
//
#include <hip/hip_runtime.h>
#include <hip/hip_bf16.h>

// x[16384,4096] fp32, v[4096,256] fp32 -> out[16384,1] fp32
// out = 0.5*(sum_f (x@v)_f^2 - sum_n x_n^2 * w_n), w_n = sum_f v_nf^2
#define B_DIM 16384
#define K_DIM 4096
#define F_DIM 256
#define BM 64
#define BK 64
#define NSTEP (K_DIM / BK)   // 64

typedef short bf16x8 __attribute__((ext_vector_type(8)));
typedef float f32x4 __attribute__((ext_vector_type(4)));

static __device__ __forceinline__ ushort f2bf(float f) {
    union { __hip_bfloat16 h; ushort s; } u;
    u.h = __float2bfloat16(f);
    return u.s;
}

static __device__ __forceinline__ void gload_lds16(const void* g, void* l) {
    __builtin_amdgcn_global_load_lds(
        (const __attribute__((address_space(1))) unsigned int*)g,
        (__attribute__((address_space(3))) unsigned int*)l, 16, 0, 0);
}

// ---- prep: w[n] = sum_f v[n][f]^2 (fp32). 8 waves/block, one row per wave.
__global__ __launch_bounds__(512) void prep_w(const float* __restrict__ v,
                                              float* __restrict__ w) {
    const int lane = threadIdx.x & 63;
    const int n = blockIdx.x * 8 + (threadIdx.x >> 6);
    const float4 vv = *reinterpret_cast<const float4*>(v + (size_t)n * F_DIM + lane * 4);
    float s = vv.x * vv.x + vv.y * vv.y + vv.z * vv.z + vv.w * vv.w;
#pragma unroll
    for (int m = 1; m < 64; m <<= 1) s += __shfl_xor(s, m);
    if (lane == 0) w[n] = s;
}

// ---- prep: vT[f][k] bf16 = v[k][f], coalesced via LDS transpose.
// block 512 thr, tile 64 k-rows x 256 f. grid 64.
__global__ __launch_bounds__(512) void prep_t(const float* __restrict__ v,
                                              ushort* __restrict__ vT) {
    __shared__ ushort T[256][72];   // pad 72 -> 144B row stride (16B aligned)
    const int tid = threadIdx.x;
    const int n0 = blockIdx.x * 64;
    const int wid = tid >> 6;
    const int f0 = (tid & 63) * 4;
#pragma unroll
    for (int j = 0; j < 8; ++j) {
        const int r = j * 8 + wid;
        const float4 vv = *reinterpret_cast<const float4*>(v + (size_t)(n0 + r) * F_DIM + f0);
        T[f0 + 0][r] = f2bf(vv.x);
        T[f0 + 1][r] = f2bf(vv.y);
        T[f0 + 2][r] = f2bf(vv.z);
        T[f0 + 3][r] = f2bf(vv.w);
    }
    __syncthreads();
    const int nb = (tid & 7) * 8;
#pragma unroll
    for (int s = 0; s < 4; ++s) {
        const int f = s * 64 + (tid >> 3);
        const uint4 val = *reinterpret_cast<const uint4*>(&T[f][nb]);
        *reinterpret_cast<uint4*>(vT + (size_t)f * K_DIM + n0 + nb) = val;
    }
}

// ---- main fused kernel: y = x@v via MFMA with LDS double-buffer;
// S1 = sum_f y^2 and S2 = sum_n x^2 w in-block; out = 0.5*(S1-S2).
// grid 256 (1 block/CU), 512 thr = 8 waves (2 row x 4 col).
__global__ __launch_bounds__(512) void fm_kernel(const float* __restrict__ x,
                                                 const ushort* __restrict__ vT,
                                                 const float* __restrict__ w,
                                                 float* __restrict__ out) {
    __shared__ ushort Ab[2][BM * BK];      // 8 KB/buf, bf16, XOR-swizzled rows
    __shared__ ushort Bb[2][F_DIM * BK];   // 32 KB/buf, bf16, XOR-swizzled rows
    __shared__ float red[BM][4];
    __shared__ float s2red[BM];

    const int tid = threadIdx.x;
    const int lane = tid & 63;
    const int wid = tid >> 6;
    const int wr = wid >> 2;   // 0..1 -> rows wr*32
    const int wc = wid & 3;    // 0..3 -> cols wc*64
    const int mbase = blockIdx.x * BM;

    // -------- staging constants (per thread) --------
    const int sr = tid >> 4;          // 0..31: owned x row (and row+32)
    const int sc = (tid & 15) * 4;    // k-elem offset within BK
    const float* gx1 = x + (size_t)(mbase + sr) * K_DIM + sc;
    const float* gx2 = x + (size_t)(mbase + 32 + sr) * K_DIM + sc;
    const float* gw = w + sc;
    const int aW1 = sr * 128 + ((sc * 2) ^ ((sr & 7) << 4));
    const int aW2 = (32 + sr) * 128 + ((sc * 2) ^ ((sr & 7) << 4));
    int bsrc[4];
#pragma unroll
    for (int i = 0; i < 4; ++i) {
        const int o = i * 8192 + tid * 16;   // linear LDS byte offset
        const int col = o >> 7;              // B row (= f col), 128 B rows
        const int j = o & 127;
        bsrc[i] = col * 8192 + (j ^ ((col & 7) << 4));   // pre-swizzled source
    }
    const char* vTb = reinterpret_cast<const char*>(vT);

    // -------- fragment read constants --------
    int aRo[2], aXm[2], bRo[4], bXm[4];
#pragma unroll
    for (int m = 0; m < 2; ++m) {
        const int r = wr * 32 + m * 16 + (lane & 15);
        aRo[m] = r * 128;
        aXm[m] = (r & 7) << 4;
    }
#pragma unroll
    for (int n = 0; n < 4; ++n) {
        const int c = wc * 64 + n * 16 + (lane & 15);
        bRo[n] = c * 128;
        bXm[n] = (c & 7) << 4;
    }
    const int kl = (lane >> 4) * 16;   // k byte offset within fragment

    float s2a = 0.f, s2b = 0.f;
    f32x4 acc[2][4] = {};
    float4 va, vb, wv;

    auto stage_load = [&](int k0, int buf) {
        va = *reinterpret_cast<const float4*>(gx1 + k0);
        vb = *reinterpret_cast<const float4*>(gx2 + k0);
        wv = *reinterpret_cast<const float4*>(gw + k0);
        char* bdst = reinterpret_cast<char*>(&Bb[buf][0]) + wid * 1024;
        const char* bs = vTb + (size_t)k0 * 2;
#pragma unroll
        for (int i = 0; i < 4; ++i)
            gload_lds16(bs + bsrc[i], bdst + i * 8192);
    };
    auto stage_store = [&](int buf) {
        s2a += va.x * va.x * wv.x + va.y * va.y * wv.y
             + va.z * va.z * wv.z + va.w * va.w * wv.w;
        s2b += vb.x * vb.x * wv.x + vb.y * vb.y * wv.y
             + vb.z * vb.z * wv.z + vb.w * vb.w * wv.w;
        uint2 pa, pb;
        pa.x = (uint)f2bf(va.x) | ((uint)f2bf(va.y) << 16);
        pa.y = (uint)f2bf(va.z) | ((uint)f2bf(va.w) << 16);
        pb.x = (uint)f2bf(vb.x) | ((uint)f2bf(vb.y) << 16);
        pb.y = (uint)f2bf(vb.z) | ((uint)f2bf(vb.w) << 16);
        char* abase = reinterpret_cast<char*>(&Ab[buf][0]);
        *reinterpret_cast<uint2*>(abase + aW1) = pa;
        *reinterpret_cast<uint2*>(abase + aW2) = pb;
    };

    // prologue: stage step 0 into buffer 0
    stage_load(0, 0);
    stage_store(0);
    __syncthreads();

    for (int kt = 0; kt < NSTEP; ++kt) {
        const int cur = kt & 1;
        const bool pf = (kt + 1) < NSTEP;
        if (pf) stage_load((kt + 1) * BK, cur ^ 1);   // loads in flight over MFMA

        const char* Ac = reinterpret_cast<const char*>(&Ab[cur][0]);
        const char* Bc = reinterpret_cast<const char*>(&Bb[cur][0]);
        bf16x8 af[2][2], bfr[4][2];
#pragma unroll
        for (int m = 0; m < 2; ++m)
#pragma unroll
            for (int ks = 0; ks < 2; ++ks)
                af[m][ks] = *reinterpret_cast<const bf16x8*>(
                    Ac + aRo[m] + ((kl + ks * 64) ^ aXm[m]));
#pragma unroll
        for (int n = 0; n < 4; ++n)
#pragma unroll
            for (int ks = 0; ks < 2; ++ks)
                bfr[n][ks] = *reinterpret_cast<const bf16x8*>(
                    Bc + bRo[n] + ((kl + ks * 64) ^ bXm[n]));
#pragma unroll
        for (int ks = 0; ks < 2; ++ks)
#pragma unroll
            for (int m = 0; m < 2; ++m)
#pragma unroll
                for (int n = 0; n < 4; ++n)
                    acc[m][n] = __builtin_amdgcn_mfma_f32_16x16x32_bf16(
                        af[m][ks], bfr[n][ks], acc[m][n], 0, 0, 0);

        if (pf) stage_store(cur ^ 1);   // vmcnt wait lands after MFMA issue
        __syncthreads();
    }

    // -------- epilogue --------
    // C/D layout: col = lane&15, row = (lane>>4)*4 + j
#pragma unroll
    for (int m = 0; m < 2; ++m) {
#pragma unroll
        for (int j = 0; j < 4; ++j) {
            float s = 0.f;
#pragma unroll
            for (int n = 0; n < 4; ++n) {
                const float y = acc[m][n][j];
                s += y * y;
            }
            s += __shfl_xor(s, 1);
            s += __shfl_xor(s, 2);
            s += __shfl_xor(s, 4);
            s += __shfl_xor(s, 8);
            if ((lane & 15) == 0)
                red[wr * 32 + m * 16 + (lane >> 4) * 4 + j][wc] = s;
        }
    }
    s2a += __shfl_xor(s2a, 1); s2a += __shfl_xor(s2a, 2);
    s2a += __shfl_xor(s2a, 4); s2a += __shfl_xor(s2a, 8);
    s2b += __shfl_xor(s2b, 1); s2b += __shfl_xor(s2b, 2);
    s2b += __shfl_xor(s2b, 4); s2b += __shfl_xor(s2b, 8);
    if ((tid & 15) == 0) {
        s2red[sr] = s2a;
        s2red[32 + sr] = s2b;
    }
    __syncthreads();
    if (tid < BM) {
        const float s1 = red[tid][0] + red[tid][1] + red[tid][2] + red[tid][3];
        out[mbase + tid] = 0.5f * (s1 - s2red[tid]);
    }
}

extern "C" void kernel_launch(void* const* d_in, const int* in_sizes, int n_in,
                              void* d_out, int out_size, void* d_ws, size_t ws_size,
                              hipStream_t stream) {
    const float* x = (const float*)d_in[0];
    const float* v = (const float*)d_in[1];
    float* out = (float*)d_out;

    // ws: [0, 2MB) vT bf16[256][4096]; then w fp32[4096]
    ushort* vT = (ushort*)d_ws;
    float* w = (float*)((char*)d_ws + (size_t)F_DIM * K_DIM * sizeof(ushort));

    prep_w<<<K_DIM / 8, 512, 0, stream>>>(v, w);
    prep_t<<<K_DIM / 64, 512, 0, stream>>>(v, vT);
    fm_kernel<<<B_DIM / BM, 512, 0, stream>>>(x, vT, w, out);
}